// Round 1
// baseline (297.118 us; speedup 1.0000x reference)
//
#include <hip/hip_runtime.h>
#include <hip/hip_bf16.h>

#define D 128
#define GROUPS_PER_BLOCK 8   // 256 threads / 32 lanes-per-row

// Each 32-lane group holds a full 128-float row as float4 per lane.
// Groups walk rows with stride 8 inside the block's contiguous chunk,
// keeping a running per-segment accumulator in registers and flushing
// via atomicAdd only when the (sorted) segment id changes.
__global__ __launch_bounds__(256)
void WeightedSum_kernel(const float* __restrict__ x,
                        const int* __restrict__ batch,
                        const float* __restrict__ mask,
                        const float* __restrict__ W,
                        const float* __restrict__ bptr,
                        float* __restrict__ out,
                        int N, int rowsPerBlock)
{
    const int tid  = threadIdx.x;
    const int lane = tid & 31;        // lane within the 32-lane row group
    const int grp  = tid >> 5;        // 0..7
    const int c0   = lane * 4;        // this lane's first column

    // W fragment + bias in registers (tiny, L2-resident broadcast)
    const float4 wv  = *reinterpret_cast<const float4*>(W + c0);
    const float bias = bptr[0];

    const int rowStart = blockIdx.x * rowsPerBlock;
    const int rowEnd   = min(rowStart + rowsPerBlock, N);

    const float4* __restrict__ x4 = reinterpret_cast<const float4*>(x);

    float4 acc = make_float4(0.f, 0.f, 0.f, 0.f);
    int cur = -1;

    for (int row = rowStart + grp; row < rowEnd; row += GROUPS_PER_BLOCK) {
        const int s = batch[row];          // broadcast load (all 32 lanes same addr)
        if (s != cur) {
            if (cur >= 0) {
                float* o = out + (size_t)cur * D + c0;
                atomicAdd(o + 0, acc.x);
                atomicAdd(o + 1, acc.y);
                atomicAdd(o + 2, acc.z);
                atomicAdd(o + 3, acc.w);
            }
            cur = s;
            acc = make_float4(0.f, 0.f, 0.f, 0.f);
        }

        const float4 xv = x4[(size_t)row * (D / 4) + lane];  // coalesced 512B/row/group
        const float  m  = mask[row];

        // partial dot, then 32-lane butterfly reduce
        float pd = xv.x * wv.x + xv.y * wv.y + xv.z * wv.z + xv.w * wv.w;
        #pragma unroll
        for (int off = 16; off >= 1; off >>= 1)
            pd += __shfl_xor(pd, off, 32);

        const float z   = pd + bias;
        const float wgt = (1.0f / (1.0f + __expf(-z))) * m;

        acc.x += wgt * xv.x;
        acc.y += wgt * xv.y;
        acc.z += wgt * xv.z;
        acc.w += wgt * xv.w;
    }

    if (cur >= 0) {
        float* o = out + (size_t)cur * D + c0;
        atomicAdd(o + 0, acc.x);
        atomicAdd(o + 1, acc.y);
        atomicAdd(o + 2, acc.z);
        atomicAdd(o + 3, acc.w);
    }
}

extern "C" void kernel_launch(void* const* d_in, const int* in_sizes, int n_in,
                              void* d_out, int out_size, void* d_ws, size_t ws_size,
                              hipStream_t stream)
{
    const float* x     = (const float*)d_in[0];
    const int*   batch = (const int*)d_in[1];
    const float* mask  = (const float*)d_in[2];
    const float* W     = (const float*)d_in[3];
    const float* b     = (const float*)d_in[4];
    // d_in[5] = num_segments (scalar); out_size = B * D already encodes it.

    float* out = (float*)d_out;
    const int N = in_sizes[1];           // batch has N elements

    // Output is accumulated with atomics -> must start from zero every call.
    hipMemsetAsync(d_out, 0, (size_t)out_size * sizeof(float), stream);

    const int nBlocks = 2048;
    const int rowsPerBlock = (N + nBlocks - 1) / nBlocks;

    WeightedSum_kernel<<<nBlocks, 256, 0, stream>>>(x, batch, mask, W, b, out,
                                                    N, rowsPerBlock);
}

// Round 3
// 244.782 us; speedup vs baseline: 1.2138x; 1.2138x over previous
//
#include <hip/hip_runtime.h>
#include <hip/hip_bf16.h>

#define D 128
#define GPB 8                  // 32-lane row-groups per 256-thread block
#define UNROLL 4               // consecutive rows per group per tile
#define ROWSTEP (GPB * UNROLL) // 32 rows per block-iteration

typedef float fx4 __attribute__((ext_vector_type(4)));  // nontemporal-compatible

// Each 32-lane group holds a full 128-float row as one float4 per lane.
// Per tile a group loads 4 consecutive rows (4 independent 512B loads in
// flight) + one int4 batch load + one float4 mask load. Sorted batch ids
// let the common case (whole pack in current segment) run branch-free;
// register accumulator flushes via atomicAdd only on segment change.
__global__ __launch_bounds__(256)
void WeightedSum_kernel(const float* __restrict__ x,
                        const int* __restrict__ batch,
                        const float* __restrict__ mask,
                        const float* __restrict__ W,
                        const float* __restrict__ bptr,
                        float* __restrict__ out,
                        int N, int rowsPerBlock)
{
    const int tid  = threadIdx.x;
    const int lane = tid & 31;
    const int grp  = tid >> 5;
    const int c0   = lane * 4;

    const float4 wv  = *reinterpret_cast<const float4*>(W + c0);
    const float bias = bptr[0];

    const int rowStart = blockIdx.x * rowsPerBlock;
    if (rowStart >= N) return;
    const int rowEnd = min(rowStart + rowsPerBlock, N);

    const fx4*    __restrict__ x4 = reinterpret_cast<const fx4*>(x);
    const int4*   __restrict__ b4 = reinterpret_cast<const int4*>(batch);
    const float4* __restrict__ m4 = reinterpret_cast<const float4*>(mask);

    float4 acc = make_float4(0.f, 0.f, 0.f, 0.f);
    int cur = -1;

    auto flush = [&](int seg) {
        float* o = out + (size_t)seg * D + c0;
        atomicAdd(o + 0, acc.x);
        atomicAdd(o + 1, acc.y);
        atomicAdd(o + 2, acc.z);
        atomicAdd(o + 3, acc.w);
        acc = make_float4(0.f, 0.f, 0.f, 0.f);
    };

    const int span  = rowEnd - rowStart;
    const int nFull = span / ROWSTEP;

    for (int t = 0; t < nFull; ++t) {
        const int base = rowStart + t * ROWSTEP + grp * UNROLL; // 4-aligned

        // pack metadata: one 16B broadcast load each
        const int4   bv = b4[base >> 2];
        const float4 mv = m4[base >> 2];

        // 4 independent 512B row loads (per wave: 8 consecutive rows = 4KB)
        const size_t rb = (size_t)base * (D / 4) + lane;
        const fx4 xv0 = __builtin_nontemporal_load(&x4[rb + 0 * (D / 4)]);
        const fx4 xv1 = __builtin_nontemporal_load(&x4[rb + 1 * (D / 4)]);
        const fx4 xv2 = __builtin_nontemporal_load(&x4[rb + 2 * (D / 4)]);
        const fx4 xv3 = __builtin_nontemporal_load(&x4[rb + 3 * (D / 4)]);

        float pd0 = xv0.x * wv.x + xv0.y * wv.y + xv0.z * wv.z + xv0.w * wv.w;
        float pd1 = xv1.x * wv.x + xv1.y * wv.y + xv1.z * wv.z + xv1.w * wv.w;
        float pd2 = xv2.x * wv.x + xv2.y * wv.y + xv2.z * wv.z + xv2.w * wv.w;
        float pd3 = xv3.x * wv.x + xv3.y * wv.y + xv3.z * wv.z + xv3.w * wv.w;

        #pragma unroll
        for (int off = 16; off >= 1; off >>= 1) {   // 4 independent chains -> ILP
            pd0 += __shfl_xor(pd0, off, 32);
            pd1 += __shfl_xor(pd1, off, 32);
            pd2 += __shfl_xor(pd2, off, 32);
            pd3 += __shfl_xor(pd3, off, 32);
        }

        const float w0 = (1.0f / (1.0f + __expf(-(pd0 + bias)))) * mv.x;
        const float w1 = (1.0f / (1.0f + __expf(-(pd1 + bias)))) * mv.y;
        const float w2 = (1.0f / (1.0f + __expf(-(pd2 + bias)))) * mv.z;
        const float w3 = (1.0f / (1.0f + __expf(-(pd3 + bias)))) * mv.w;

        if (bv.x == cur && bv.w == cur) {
            // fast path: whole pack stays in the current segment (sorted ids)
            acc.x += w0 * xv0.x + w1 * xv1.x + w2 * xv2.x + w3 * xv3.x;
            acc.y += w0 * xv0.y + w1 * xv1.y + w2 * xv2.y + w3 * xv3.y;
            acc.z += w0 * xv0.z + w1 * xv1.z + w2 * xv2.z + w3 * xv3.z;
            acc.w += w0 * xv0.w + w1 * xv1.w + w2 * xv2.w + w3 * xv3.w;
        } else {
            const int   sv[4] = { bv.x, bv.y, bv.z, bv.w };
            const float wk[4] = { w0, w1, w2, w3 };
            const fx4   xk[4] = { xv0, xv1, xv2, xv3 };
            #pragma unroll
            for (int k = 0; k < 4; ++k) {
                if (sv[k] != cur) {
                    if (cur >= 0) flush(cur);
                    cur = sv[k];
                }
                acc.x += wk[k] * xk[k].x;
                acc.y += wk[k] * xk[k].y;
                acc.z += wk[k] * xk[k].z;
                acc.w += wk[k] * xk[k].w;
            }
        }
    }

    // tail rows (span not a multiple of 32), original strided pattern
    for (int row = rowStart + nFull * ROWSTEP + grp; row < rowEnd; row += GPB) {
        const int s = batch[row];
        if (s != cur) {
            if (cur >= 0) flush(cur);
            cur = s;
        }
        const fx4 xv = x4[(size_t)row * (D / 4) + lane];
        const float m = mask[row];
        float pd = xv.x * wv.x + xv.y * wv.y + xv.z * wv.z + xv.w * wv.w;
        #pragma unroll
        for (int off = 16; off >= 1; off >>= 1)
            pd += __shfl_xor(pd, off, 32);
        const float wgt = (1.0f / (1.0f + __expf(-(pd + bias)))) * m;
        acc.x += wgt * xv.x;
        acc.y += wgt * xv.y;
        acc.z += wgt * xv.z;
        acc.w += wgt * xv.w;
    }

    if (cur >= 0) flush(cur);
}

extern "C" void kernel_launch(void* const* d_in, const int* in_sizes, int n_in,
                              void* d_out, int out_size, void* d_ws, size_t ws_size,
                              hipStream_t stream)
{
    const float* x     = (const float*)d_in[0];
    const int*   batch = (const int*)d_in[1];
    const float* mask  = (const float*)d_in[2];
    const float* W     = (const float*)d_in[3];
    const float* b     = (const float*)d_in[4];

    float* out = (float*)d_out;
    const int N = in_sizes[1];

    // atomically accumulated -> zero first (harness poisons with 0xAA)
    (void)hipMemsetAsync(d_out, 0, (size_t)out_size * sizeof(float), stream);

    const int nBlocks = 2048;
    // multiple of ROWSTEP so per-pack int4/float4 index loads stay 16B-aligned
    const int rowsPerBlock = (((N + nBlocks - 1) / nBlocks) + ROWSTEP - 1) & ~(ROWSTEP - 1);

    WeightedSum_kernel<<<nBlocks, 256, 0, stream>>>(x, batch, mask, W, b, out,
                                                    N, rowsPerBlock);
}

// Round 4
// 238.199 us; speedup vs baseline: 1.2474x; 1.0276x over previous
//
#include <hip/hip_runtime.h>
#include <hip/hip_bf16.h>

#define D 128
#define GPB 8                  // 32-lane row-groups per 256-thread block
#define UNROLL 8               // consecutive rows per group per tile
#define ROWSTEP (GPB * UNROLL) // 64 rows per block-iteration

typedef float fx4 __attribute__((ext_vector_type(4)));

// Each 32-lane group holds a full 128-float row as one float4 per lane.
// Register double-buffer: pack t+1's 8 row-loads + metadata are issued
// BEFORE computing pack t, so ~8 x 512B stay in flight per group across
// the whole compute phase. Sorted batch ids -> branch-free fast path;
// register accumulator flushes via atomicAdd only on segment change.
__global__ __launch_bounds__(256)
void WeightedSum_kernel(const float* __restrict__ x,
                        const int* __restrict__ batch,
                        const float* __restrict__ mask,
                        const float* __restrict__ W,
                        const float* __restrict__ bptr,
                        float* __restrict__ out,
                        int N, int rowsPerBlock)
{
    const int tid  = threadIdx.x;
    const int lane = tid & 31;
    const int grp  = tid >> 5;
    const int c0   = lane * 4;

    const float4 wv  = *reinterpret_cast<const float4*>(W + c0);
    const float bias = bptr[0];

    const int rowStart = blockIdx.x * rowsPerBlock;
    if (rowStart >= N) return;
    const int rowEnd = min(rowStart + rowsPerBlock, N);

    const fx4*    __restrict__ x4 = reinterpret_cast<const fx4*>(x);
    const int4*   __restrict__ b4 = reinterpret_cast<const int4*>(batch);
    const float4* __restrict__ m4 = reinterpret_cast<const float4*>(mask);

    float4 acc = make_float4(0.f, 0.f, 0.f, 0.f);
    int cur = -1;

    auto flush = [&](int seg) {
        float* o = out + (size_t)seg * D + c0;
        atomicAdd(o + 0, acc.x);
        atomicAdd(o + 1, acc.y);
        atomicAdd(o + 2, acc.z);
        atomicAdd(o + 3, acc.w);
        acc = make_float4(0.f, 0.f, 0.f, 0.f);
    };

    const int span  = rowEnd - rowStart;
    const int nFull = span / ROWSTEP;

    fx4    xa[UNROLL];
    int4   ba[2];
    float4 ma[2];

    auto issue = [&](int base, fx4* xv, int4* bv, float4* mv) {
        bv[0] = b4[(base >> 2) + 0];
        bv[1] = b4[(base >> 2) + 1];
        mv[0] = m4[(base >> 2) + 0];
        mv[1] = m4[(base >> 2) + 1];
        const size_t rb = (size_t)base * (D / 4) + lane;
        #pragma unroll
        for (int k = 0; k < UNROLL; ++k)
            xv[k] = __builtin_nontemporal_load(&x4[rb + (size_t)k * (D / 4)]);
    };

    if (nFull > 0)
        issue(rowStart + grp * UNROLL, xa, ba, ma);   // prologue: pack 0

    for (int t = 0; t < nFull; ++t) {
        // --- prefetch pack t+1 into the B buffer (clamped to stay in-bounds)
        const int tn = (t + 1 < nFull) ? (t + 1) : t;
        fx4    xb[UNROLL];
        int4   bb[2];
        float4 mb[2];
        issue(rowStart + tn * ROWSTEP + grp * UNROLL, xb, bb, mb);

        // --- compute pack t from the A buffer
        float pd[UNROLL];
        #pragma unroll
        for (int k = 0; k < UNROLL; ++k)
            pd[k] = xa[k].x * wv.x + xa[k].y * wv.y + xa[k].z * wv.z + xa[k].w * wv.w;

        #pragma unroll
        for (int off = 16; off >= 1; off >>= 1) {    // 8 independent chains -> ILP
            #pragma unroll
            for (int k = 0; k < UNROLL; ++k)
                pd[k] += __shfl_xor(pd[k], off, 32);
        }

        float wk[UNROLL];
        const float mm[8] = { ma[0].x, ma[0].y, ma[0].z, ma[0].w,
                              ma[1].x, ma[1].y, ma[1].z, ma[1].w };
        #pragma unroll
        for (int k = 0; k < UNROLL; ++k)
            wk[k] = (1.0f / (1.0f + __expf(-(pd[k] + bias)))) * mm[k];

        if (ba[0].x == cur && ba[1].w == cur) {
            // fast path: whole pack stays in the current segment (sorted ids)
            #pragma unroll
            for (int k = 0; k < UNROLL; ++k) {
                acc.x += wk[k] * xa[k].x;
                acc.y += wk[k] * xa[k].y;
                acc.z += wk[k] * xa[k].z;
                acc.w += wk[k] * xa[k].w;
            }
        } else {
            const int sv[8] = { ba[0].x, ba[0].y, ba[0].z, ba[0].w,
                                ba[1].x, ba[1].y, ba[1].z, ba[1].w };
            #pragma unroll
            for (int k = 0; k < UNROLL; ++k) {
                if (sv[k] != cur) {
                    if (cur >= 0) flush(cur);
                    cur = sv[k];
                }
                acc.x += wk[k] * xa[k].x;
                acc.y += wk[k] * xa[k].y;
                acc.z += wk[k] * xa[k].z;
                acc.w += wk[k] * xa[k].w;
            }
        }

        // --- rotate B -> A (register renaming, no real moves after unroll)
        #pragma unroll
        for (int k = 0; k < UNROLL; ++k) xa[k] = xb[k];
        ba[0] = bb[0]; ba[1] = bb[1];
        ma[0] = mb[0]; ma[1] = mb[1];
    }

    // tail rows (span not a multiple of 64), original strided pattern
    for (int row = rowStart + nFull * ROWSTEP + grp; row < rowEnd; row += GPB) {
        const int s = batch[row];
        if (s != cur) {
            if (cur >= 0) flush(cur);
            cur = s;
        }
        const fx4 xv = x4[(size_t)row * (D / 4) + lane];
        const float m = mask[row];
        float pd = xv.x * wv.x + xv.y * wv.y + xv.z * wv.z + xv.w * wv.w;
        #pragma unroll
        for (int off = 16; off >= 1; off >>= 1)
            pd += __shfl_xor(pd, off, 32);
        const float wgt = (1.0f / (1.0f + __expf(-(pd + bias)))) * m;
        acc.x += wgt * xv.x;
        acc.y += wgt * xv.y;
        acc.z += wgt * xv.z;
        acc.w += wgt * xv.w;
    }

    if (cur >= 0) flush(cur);
}

extern "C" void kernel_launch(void* const* d_in, const int* in_sizes, int n_in,
                              void* d_out, int out_size, void* d_ws, size_t ws_size,
                              hipStream_t stream)
{
    const float* x     = (const float*)d_in[0];
    const int*   batch = (const int*)d_in[1];
    const float* mask  = (const float*)d_in[2];
    const float* W     = (const float*)d_in[3];
    const float* b     = (const float*)d_in[4];

    float* out = (float*)d_out;
    const int N = in_sizes[1];

    // atomically accumulated -> zero first (harness poisons with 0xAA)
    (void)hipMemsetAsync(d_out, 0, (size_t)out_size * sizeof(float), stream);

    const int nBlocks = 2048;
    // multiple of ROWSTEP so per-pack int4/float4 index loads stay 16B-aligned
    const int rowsPerBlock = (((N + nBlocks - 1) / nBlocks) + ROWSTEP - 1) & ~(ROWSTEP - 1);

    WeightedSum_kernel<<<nBlocks, 256, 0, stream>>>(x, batch, mask, W, b, out,
                                                    N, rowsPerBlock);
}